// Round 1
// baseline (223.652 us; speedup 1.0000x reference)
//
#include <hip/hip_runtime.h>

// roll(cache, -64, axis=1) then last 64 rows := x.
// B=4, S=8192, D=1024, n=64, fp32.
// Flat float4 view: D4 = 256 float4/row, SHIFT4 = 64*1024/4 = 16384.
// For s < S-n: out[idx] = cache[idx + SHIFT4]  (shift stays within batch b)
// For s >= S-n: out[idx] = x[(b*64 + (s-(S-n)))*256 + d4]

__global__ __launch_bounds__(256) void roll_set_kernel(
    const float4* __restrict__ x4,
    const float4* __restrict__ cache4,
    float4* __restrict__ out4,
    int total4) {
    int idx = blockIdx.x * blockDim.x + threadIdx.x;
    if (idx >= total4) return;

    const int D4     = 256;    // 1024 / 4
    const int S      = 8192;
    const int n      = 64;
    const int SHIFT4 = n * D4; // 16384

    int row = idx >> 8;        // idx / D4
    int s   = row & (S - 1);   // row % S
    float4 v;
    if (s < S - n) {
        // bulk: flat-shifted copy (wave-uniform branch: all 64 lanes share a row)
        v = cache4[idx + SHIFT4];
    } else {
        int b = row >> 13;     // row / S
        int i = s - (S - n);   // 0..63
        v = x4[(b * n + i) * D4 + (idx & (D4 - 1))];
    }
    out4[idx] = v;
}

extern "C" void kernel_launch(void* const* d_in, const int* in_sizes, int n_in,
                              void* d_out, int out_size, void* d_ws, size_t ws_size,
                              hipStream_t stream) {
    const float* x     = (const float*)d_in[0];   // [4, 64, 1024] fp32
    const float* cache = (const float*)d_in[1];   // [4, 8192, 1024] fp32
    float* out         = (float*)d_out;           // [4, 8192, 1024] fp32

    int total4  = out_size / 4;                   // 8,388,608 float4
    int threads = 256;
    int blocks  = (total4 + threads - 1) / threads;

    roll_set_kernel<<<blocks, threads, 0, stream>>>(
        (const float4*)x, (const float4*)cache, (float4*)out, total4);
}